// Round 2
// baseline (142.424 us; speedup 1.0000x reference)
//
#include <hip/hip_runtime.h>
#include <math.h>

#define NBATCH 16
#define NANCH  3
#define NHH    64
#define NWW    64
#define NTT    50
#define NCLS   80
#define HW     (NHH*NWW)          // 4096
#define CELLS  (NBATCH*NANCH*HW)  // 196608
#define CELLBLOCKS (CELLS/256)    // 768

// anchors / stride
#define AW0 1.875f
#define AW1 3.875f
#define AW2 3.6875f
#define AH0 3.8125f
#define AH1 2.8125f
#define AH2 7.4375f

__device__ __forceinline__ void prep_targets(const float* __restrict__ target, int b, int tid,
                                             float* s_gx, float* s_gy, float* s_gw, float* s_gh,
                                             int* s_meta) {
    if (tid < NTT) {
        const float* tb0 = target + b * (NTT * 5);
        const float* tb  = tb0 + tid * 5;
        bool valid = true;
        for (int tt = 0; tt <= tid; ++tt)
            if (tb0[tt * 5 + 1] == 0.0f) { valid = false; break; }

        float gx = tb[1] * NWW, gy = tb[2] * NHH;
        float gw = tb[3] * NWW, gh = tb[4] * NHH;

        float ga = gw * gh;
        float i0 = fminf(gw, AW0) * fminf(gh, AH0);
        float i1 = fminf(gw, AW1) * fminf(gh, AH1);
        float i2 = fminf(gw, AW2) * fminf(gh, AH2);
        float r0 = i0 / (ga + AW0 * AH0 - i0);
        float r1 = i1 / (ga + AW1 * AH1 - i1);
        float r2 = i2 / (ga + AW2 * AH2 - i2);
        int best = 0; float bv = r0;
        if (r1 > bv) { bv = r1; best = 1; }
        if (r2 > bv) { bv = r2; best = 2; }

        int gi = (int)floorf(gx); gi = gi < 0 ? 0 : (gi > NWW - 1 ? NWW - 1 : gi);
        int gj = (int)floorf(gy); gj = gj < 0 ? 0 : (gj > NHH - 1 ? NHH - 1 : gj);

        s_gx[tid] = gx; s_gy[tid] = gy; s_gw[tid] = gw; s_gh[tid] = gh;
        s_meta[tid] = valid ? ((1 << 15) | (best << 12) | (gj << 6) | gi) : 0;
    }
}

__global__ __launch_bounds__(256) void yolo_loss_kernel(
    const float* __restrict__ out,     // (16, 255, 64, 64)
    const float* __restrict__ target,  // (16, 250)
    float* __restrict__ loss)          // scalar, pre-zeroed
{
    __shared__ float s_gx[NTT], s_gy[NTT], s_gw[NTT], s_gh[NTT];
    __shared__ int   s_meta[NTT];
    __shared__ float s_part[4];

    const int tid = threadIdx.x;

    if (blockIdx.x >= CELLBLOCKS) {
        // ================= target blocks: class NLL =================
        const int b = blockIdx.x - CELLBLOCKS;
        prep_targets(target, b, tid, s_gx, s_gy, s_gw, s_gh, s_meta);
        __syncthreads();

        const int lane = tid & 63, wid = tid >> 6;
        float wsum = 0.0f;
        for (int t = wid; t < NTT; t += 4) {
            const int m = s_meta[t];
            if (m == 0) continue;
            // "last valid t wins": skip if any later valid t maps to same cell
            bool dup = false;
            for (int t2 = t + 1; t2 < NTT; ++t2)
                if (s_meta[t2] == m) { dup = true; break; }
            if (dup) continue;

            const int best = (m >> 12) & 3;
            const int hw   = m & 0xFFF;  // gj<<6|gi
            const float* cb = out + ((size_t)(b * NANCH + best) * (5 + NCLS) + 5) * HW + hw;

            // lanes load classes lane and lane+64 in parallel
            const float l0 = cb[lane * HW];
            const float l1 = (lane < NCLS - 64) ? cb[(lane + 64) * HW] : -INFINITY;

            float mv = fmaxf(l0, l1);
            #pragma unroll
            for (int off = 32; off > 0; off >>= 1)
                mv = fmaxf(mv, __shfl_xor(mv, off, 64));

            float e = __expf(l0 - mv) * 0.0f + expf(l0 - mv);
            e = expf(l0 - mv) + ((lane < NCLS - 64) ? expf(l1 - mv) : 0.0f);
            #pragma unroll
            for (int off = 32; off > 0; off >>= 1)
                e += __shfl_xor(e, off, 64);

            if (lane == 0) {
                const int tc = (int)target[b * (NTT * 5) + t * 5];
                const float lt = cb[tc * HW];
                wsum += -(lt - mv - logf(e));
            }
        }
        if (lane == 0 && wsum != 0.0f) atomicAdd(loss, wsum);
        return;
    }

    // ================= cell blocks =================
    const int b = blockIdx.x / 48;
    prep_targets(target, b, tid, s_gx, s_gy, s_gw, s_gh, s_meta);
    __syncthreads();

    const int cell = blockIdx.x * 256 + tid;
    const int rem  = cell % (NANCH * HW);
    const int a    = rem / HW;
    const int hw   = rem % HW;
    const int h    = hw >> 6;
    const int w    = hw & 63;

    const float* base = out + ((size_t)b * (NANCH * (5 + NCLS)) + (size_t)a * (5 + NCLS)) * HW + hw;
    const float r0 = base[0];
    const float r1 = base[HW];
    const float r2 = base[2 * HW];
    const float r3 = base[3 * HW];
    const float r4 = base[4 * HW];

    const float sx = 1.0f / (1.0f + expf(-r0));
    const float sy = 1.0f / (1.0f + expf(-r1));

    // reference's anchor-broadcast quirk: effective anchor = (3b+a)//16
    const int aidx = (3 * b + a) >> 4;
    const float aw = aidx == 0 ? AW0 : (aidx == 1 ? AW1 : AW2);
    const float ah = aidx == 0 ? AH0 : (aidx == 1 ? AH1 : AH2);

    const float px = sx + (float)w;
    const float py = sy + (float)h;
    const float pw = expf(r2) * aw;
    const float ph = expf(r3) * ah;

    const float hx0 = px - pw * 0.5f, hx1 = px + pw * 0.5f;
    const float hy0 = py - ph * 0.5f, hy1 = py + ph * 0.5f;

    const int key = (1 << 15) | (a << 12) | (h << 6) | w;  // matches meta iff valid & same cell

    float curmax = 0.0f;
    int   tlast  = -1;
    #pragma unroll 1
    for (int t = 0; t < NTT; ++t) {
        const int m = s_meta[t];
        if (m != 0) {
            const float gx = s_gx[t], gy = s_gy[t];
            const float gw = s_gw[t], gh = s_gh[t];
            const float mx = fminf(hx0, gx - gw * 0.5f);
            const float Mx = fmaxf(hx1, gx + gw * 0.5f);
            const float my = fminf(hy0, gy - gh * 0.5f);
            const float My = fmaxf(hy1, gy + gh * 0.5f);
            const float cw = pw + gw - (Mx - mx);
            const float ch = ph + gh - (My - my);
            const float carea = (cw <= 0.0f || ch <= 0.0f) ? 0.0f : cw * ch;
            const float uarea = pw * ph + gw * gh - carea;
            curmax = fmaxf(curmax, carea / uarea);
            if (m == key) tlast = t;  // last valid t wins
        }
    }

    const float conf = 1.0f / (1.0f + expf(-r4));
    float lsum;
    if (tlast >= 0) {
        const int m    = s_meta[tlast];
        const int best = (m >> 12) & 3;
        const float baw = best == 0 ? AW0 : (best == 1 ? AW1 : AW2);
        const float bah = best == 0 ? AH0 : (best == 1 ? AH1 : AH2);
        const float tx = s_gx[tlast] - (float)(m & 63);
        const float ty = s_gy[tlast] - (float)((m >> 6) & 63);
        const float tw = logf(s_gw[tlast] / baw);
        const float th = logf(s_gh[tlast] / bah);

        const float dx = sx - tx, dy = sy - ty, dw = r2 - tw, dh = r3 - th;
        const float dc = conf - 1.0f;
        lsum = dc * dc + 0.5f * (dx * dx + dy * dy + dw * dw + dh * dh);
    } else {
        lsum = (curmax > 0.5f) ? 0.0f : conf * conf;
    }

    // ---- reduce: wave shuffle -> LDS -> one atomic per block ----
    float v = lsum;
    #pragma unroll
    for (int off = 32; off > 0; off >>= 1) v += __shfl_down(v, off, 64);
    const int lane = tid & 63, wid = tid >> 6;
    if (lane == 0) s_part[wid] = v;
    __syncthreads();
    if (tid == 0)
        atomicAdd(loss, s_part[0] + s_part[1] + s_part[2] + s_part[3]);
}

extern "C" void kernel_launch(void* const* d_in, const int* in_sizes, int n_in,
                              void* d_out, int out_size, void* d_ws, size_t ws_size,
                              hipStream_t stream) {
    const float* out_t  = (const float*)d_in[0];   // (16, 255, 64, 64) f32
    const float* target = (const float*)d_in[1];   // (16, 250) f32
    float* loss = (float*)d_out;

    hipMemsetAsync(loss, 0, sizeof(float), stream);
    yolo_loss_kernel<<<CELLBLOCKS + NBATCH, 256, 0, stream>>>(out_t, target, loss);
}

// Round 3
// 107.537 us; speedup vs baseline: 1.3244x; 1.3244x over previous
//
#include <hip/hip_runtime.h>
#include <math.h>

#define NBATCH 16
#define NANCH  3
#define NHH    64
#define NWW    64
#define NTT    50
#define NCLS   80
#define HW     (NHH*NWW)          // 4096
#define CELLS  (NBATCH*NANCH*HW)  // 196608
#define CELLBLOCKS (CELLS/256)    // 768
#define TPB    13                 // target blocks per batch (4 waves/block -> 52 >= 50)
#define TBLOCKS (NBATCH*TPB)      // 208

// anchors / stride
#define AW0 1.875f
#define AW1 3.875f
#define AW2 3.6875f
#define AH0 3.8125f
#define AH1 2.8125f
#define AH2 7.4375f

// Wave-0-only target prep: one coalesced load + ballot-based cumprod validity.
// Replaces the serial 50-load validity chain (R1 bottleneck).
__device__ __forceinline__ void prep_targets(const float* __restrict__ target, int b, int tid,
                                             float* s_gx, float* s_gy, float* s_gw, float* s_gh,
                                             float* s_xlo, float* s_xhi, float* s_ylo, float* s_yhi,
                                             float* s_area, int* s_meta) {
    // caller guarantees tid < 64 (wave 0)
    const float* tb0 = target + b * (NTT * 5);
    float c1 = 0.f, c2 = 0.f, c3 = 0.f, c4 = 0.f;
    bool nz = false;
    if (tid < NTT) {
        c1 = tb0[tid * 5 + 1]; c2 = tb0[tid * 5 + 2];
        c3 = tb0[tid * 5 + 3]; c4 = tb0[tid * 5 + 4];
        nz = (c1 != 0.0f);
    }
    const unsigned long long mask = __ballot(nz);
    const int first_zero = __ffsll((unsigned long long)~mask) - 1;  // cumprod boundary
    if (tid < NTT) {
        const bool valid = tid < first_zero;
        const float gx = c1 * NWW, gy = c2 * NHH;
        const float gw = c3 * NWW, gh = c4 * NHH;

        // best anchor (first max wins)
        const float ga = gw * gh;
        const float i0 = fminf(gw, AW0) * fminf(gh, AH0);
        const float i1 = fminf(gw, AW1) * fminf(gh, AH1);
        const float i2 = fminf(gw, AW2) * fminf(gh, AH2);
        const float r0 = i0 / (ga + AW0 * AH0 - i0);
        const float r1 = i1 / (ga + AW1 * AH1 - i1);
        const float r2 = i2 / (ga + AW2 * AH2 - i2);
        int best = 0; float bv = r0;
        if (r1 > bv) { bv = r1; best = 1; }
        if (r2 > bv) { bv = r2; best = 2; }

        int gi = (int)floorf(gx); gi = gi < 0 ? 0 : (gi > NWW - 1 ? NWW - 1 : gi);
        int gj = (int)floorf(gy); gj = gj < 0 ? 0 : (gj > NHH - 1 ? NHH - 1 : gj);

        s_gx[tid] = gx; s_gy[tid] = gy; s_gw[tid] = gw; s_gh[tid] = gh;
        s_xlo[tid] = gx - gw * 0.5f; s_xhi[tid] = gx + gw * 0.5f;
        s_ylo[tid] = gy - gh * 0.5f; s_yhi[tid] = gy + gh * 0.5f;
        s_area[tid] = ga;
        s_meta[tid] = valid ? ((1 << 15) | (best << 12) | (gj << 6) | gi) : 0;
    }
}

__global__ __launch_bounds__(256) void yolo_loss_kernel(
    const float* __restrict__ out,     // (16, 255, 64, 64)
    const float* __restrict__ target,  // (16, 250)
    float* __restrict__ loss)          // scalar, pre-zeroed
{
    __shared__ float s_gx[NTT], s_gy[NTT], s_gw[NTT], s_gh[NTT];
    __shared__ float s_xlo[NTT], s_xhi[NTT], s_ylo[NTT], s_yhi[NTT], s_area[NTT];
    __shared__ int   s_meta[NTT];
    __shared__ float s_part[4];

    const int tid  = threadIdx.x;
    const int lane = tid & 63, wid = tid >> 6;

    if (blockIdx.x < TBLOCKS) {
        // ============ target blocks: one wave per (b,t), class NLL ============
        const int tb = blockIdx.x;
        const int b  = tb / TPB;
        const int t  = (tb % TPB) * 4 + wid;

        if (tid < 64)
            prep_targets(target, b, tid, s_gx, s_gy, s_gw, s_gh,
                         s_xlo, s_xhi, s_ylo, s_yhi, s_area, s_meta);
        __syncthreads();

        if (t < NTT) {
            const int m = s_meta[t];            // wave-uniform
            if (m != 0) {
                // "last valid t wins": skip if any later t has the same cell key
                const int mv_lane = (lane < NTT) ? s_meta[lane] : 0;
                const unsigned long long dup = __ballot(lane > t && mv_lane == m);
                if (dup == 0ULL) {
                    const int best = (m >> 12) & 3;
                    const int hw   = m & 0xFFF;
                    const float* cb = out + ((size_t)(b * NANCH + best) * (5 + NCLS) + 5) * HW + hw;

                    const float l0 = cb[lane * HW];
                    const float l1 = (lane < NCLS - 64) ? cb[(lane + 64) * HW] : -INFINITY;

                    float mx = fmaxf(l0, l1);
                    #pragma unroll
                    for (int off = 32; off > 0; off >>= 1)
                        mx = fmaxf(mx, __shfl_xor(mx, off, 64));

                    float e = __expf(l0 - mx) + ((lane < NCLS - 64) ? __expf(l1 - mx) : 0.0f);
                    #pragma unroll
                    for (int off = 32; off > 0; off >>= 1)
                        e += __shfl_xor(e, off, 64);

                    if (lane == 0) {
                        const int tc = (int)target[b * (NTT * 5) + t * 5];
                        const float lt = cb[tc * HW];
                        atomicAdd(loss, -(lt - mx - __logf(e)));
                    }
                }
            }
        }
        return;
    }

    // ============ cell blocks ============
    const int cblk = blockIdx.x - TBLOCKS;
    const int b    = cblk / 48;

    const int cell = cblk * 256 + tid;
    const int rem  = cell % (NANCH * HW);
    const int a    = rem / HW;
    const int hw   = rem % HW;
    const int h    = hw >> 6;
    const int w    = hw & 63;

    // issue the 5 strided cell loads before the prep barrier (latency overlap)
    const float* base = out + ((size_t)b * (NANCH * (5 + NCLS)) + (size_t)a * (5 + NCLS)) * HW + hw;
    const float r0 = base[0];
    const float r1 = base[HW];
    const float r2 = base[2 * HW];
    const float r3 = base[3 * HW];
    const float r4 = base[4 * HW];

    if (tid < 64)
        prep_targets(target, b, tid, s_gx, s_gy, s_gw, s_gh,
                     s_xlo, s_xhi, s_ylo, s_yhi, s_area, s_meta);
    __syncthreads();

    const float sx = __builtin_amdgcn_rcpf(1.0f + __expf(-r0));
    const float sy = __builtin_amdgcn_rcpf(1.0f + __expf(-r1));

    // reference's anchor-broadcast quirk: effective anchor = (3b+a)//16
    const int aidx = (3 * b + a) >> 4;
    const float aw = aidx == 0 ? AW0 : (aidx == 1 ? AW1 : AW2);
    const float ah = aidx == 0 ? AH0 : (aidx == 1 ? AH1 : AH2);

    const float px = sx + (float)w;
    const float py = sy + (float)h;
    const float pw = __expf(r2) * aw;
    const float ph = __expf(r3) * ah;
    const float parea = pw * ph;

    const float hx0 = px - pw * 0.5f, hx1 = px + pw * 0.5f;
    const float hy0 = py - ph * 0.5f, hy1 = py + ph * 0.5f;

    const int key = (1 << 15) | (a << 12) | (h << 6) | w;

    float curmax = 0.0f;
    int   tlast  = -1;
    #pragma unroll 5
    for (int t = 0; t < NTT; ++t) {
        const int   m   = s_meta[t];
        const float xlo = s_xlo[t], xhi = s_xhi[t];
        const float ylo = s_ylo[t], yhi = s_yhi[t];
        const float ga  = s_area[t];
        const float mx = fminf(hx0, xlo), Mx = fmaxf(hx1, xhi);
        const float my = fminf(hy0, ylo), My = fmaxf(hy1, yhi);
        const float cw = (pw + (xhi - xlo)) - (Mx - mx);
        const float ch = (ph + (yhi - ylo)) - (My - my);
        const float carea = (cw <= 0.0f || ch <= 0.0f) ? 0.0f : cw * ch;
        const float uarea = parea + ga - carea;
        const float iou   = carea * __builtin_amdgcn_rcpf(uarea);
        curmax = fmaxf(curmax, (m != 0) ? iou : 0.0f);
        if (m == key) tlast = t;   // key has valid bit set; last valid t wins
    }

    const float conf = __builtin_amdgcn_rcpf(1.0f + __expf(-r4));
    float lsum;
    if (tlast >= 0) {
        const int best = (s_meta[tlast] >> 12) & 3;
        const float baw = best == 0 ? AW0 : (best == 1 ? AW1 : AW2);
        const float bah = best == 0 ? AH0 : (best == 1 ? AH1 : AH2);
        const float tx = s_gx[tlast] - (float)w;
        const float ty = s_gy[tlast] - (float)h;
        const float tw = __logf(s_gw[tlast] * __builtin_amdgcn_rcpf(baw));
        const float th = __logf(s_gh[tlast] * __builtin_amdgcn_rcpf(bah));

        const float dx = sx - tx, dy = sy - ty, dw = r2 - tw, dh = r3 - th;
        const float dc = conf - 1.0f;
        lsum = dc * dc + 0.5f * (dx * dx + dy * dy + dw * dw + dh * dh);
    } else {
        lsum = (curmax > 0.5f) ? 0.0f : conf * conf;
    }

    // reduce: wave shuffle -> LDS -> one atomic per block
    float v = lsum;
    #pragma unroll
    for (int off = 32; off > 0; off >>= 1) v += __shfl_down(v, off, 64);
    if (lane == 0) s_part[wid] = v;
    __syncthreads();
    if (tid == 0)
        atomicAdd(loss, s_part[0] + s_part[1] + s_part[2] + s_part[3]);
}

extern "C" void kernel_launch(void* const* d_in, const int* in_sizes, int n_in,
                              void* d_out, int out_size, void* d_ws, size_t ws_size,
                              hipStream_t stream) {
    const float* out_t  = (const float*)d_in[0];   // (16, 255, 64, 64) f32
    const float* target = (const float*)d_in[1];   // (16, 250) f32
    float* loss = (float*)d_out;

    hipMemsetAsync(loss, 0, sizeof(float), stream);
    yolo_loss_kernel<<<TBLOCKS + CELLBLOCKS, 256, 0, stream>>>(out_t, target, loss);
}

// Round 5
// 96.128 us; speedup vs baseline: 1.4816x; 1.1187x over previous
//
#include <hip/hip_runtime.h>
#include <math.h>

#define NBATCH 16
#define NANCH  3
#define NHH    64
#define NWW    64
#define NTT    50
#define NCLS   80
#define HW     (NHH*NWW)          // 4096
#define CELLS  (NBATCH*NANCH*HW)  // 196608
#define CELLBLOCKS (CELLS/256)    // 768
#define TPB    13                 // target blocks per batch (4 waves/block -> 52 >= 50)
#define TBLOCKS (NBATCH*TPB)      // 208
#define NPART  (TBLOCKS + CELLBLOCKS)  // 976 partials

// anchors / stride
#define AW0 1.875f
#define AW1 3.875f
#define AW2 3.6875f
#define AH0 3.8125f
#define AH1 2.8125f
#define AH2 7.4375f

// Wave-0-only target prep: one coalesced load + ballot-based cumprod validity.
__device__ __forceinline__ void prep_targets(const float* __restrict__ target, int b, int tid,
                                             float* s_gx, float* s_gy, float* s_gw, float* s_gh,
                                             float4* s_box, float2* s_gam, int* s_meta) {
    // caller guarantees tid < 64 (wave 0)
    const float* tb0 = target + b * (NTT * 5);
    float c1 = 0.f, c2 = 0.f, c3 = 0.f, c4 = 0.f;
    bool nz = false;
    if (tid < NTT) {
        c1 = tb0[tid * 5 + 1]; c2 = tb0[tid * 5 + 2];
        c3 = tb0[tid * 5 + 3]; c4 = tb0[tid * 5 + 4];
        nz = (c1 != 0.0f);
    }
    const unsigned long long mask = __ballot(nz);
    const int first_zero = __ffsll((unsigned long long)~mask) - 1;  // cumprod boundary
    if (tid < NTT) {
        const bool valid = tid < first_zero;
        const float gx = c1 * NWW, gy = c2 * NHH;
        const float gw = c3 * NWW, gh = c4 * NHH;

        // best anchor (first max wins)
        const float ga = gw * gh;
        const float i0 = fminf(gw, AW0) * fminf(gh, AH0);
        const float i1 = fminf(gw, AW1) * fminf(gh, AH1);
        const float i2 = fminf(gw, AW2) * fminf(gh, AH2);
        const float r0 = i0 / (ga + AW0 * AH0 - i0);
        const float r1 = i1 / (ga + AW1 * AH1 - i1);
        const float r2 = i2 / (ga + AW2 * AH2 - i2);
        int best = 0; float bv = r0;
        if (r1 > bv) { bv = r1; best = 1; }
        if (r2 > bv) { bv = r2; best = 2; }

        int gi = (int)floorf(gx); gi = gi < 0 ? 0 : (gi > NWW - 1 ? NWW - 1 : gi);
        int gj = (int)floorf(gy); gj = gj < 0 ? 0 : (gj > NHH - 1 ? NHH - 1 : gj);

        const int m = valid ? ((1 << 15) | (best << 12) | (gj << 6) | gi) : 0;
        s_gx[tid] = gx; s_gy[tid] = gy; s_gw[tid] = gw; s_gh[tid] = gh;
        s_box[tid] = make_float4(gx - gw * 0.5f, gx + gw * 0.5f,
                                 gy - gh * 0.5f, gy + gh * 0.5f);
        s_gam[tid] = make_float2(ga, __int_as_float(m));
        s_meta[tid] = m;
    }
}

__global__ __launch_bounds__(256) void yolo_loss_kernel(
    const float* __restrict__ out,     // (16, 255, 64, 64)
    const float* __restrict__ target,  // (16, 250)
    float* __restrict__ partials)      // NPART slots in d_ws
{
    __shared__ float  s_gx[NTT], s_gy[NTT], s_gw[NTT], s_gh[NTT];
    __shared__ float4 s_box[NTT];
    __shared__ float2 s_gam[NTT];
    __shared__ int    s_meta[NTT];
    __shared__ float  s_part[4];

    const int tid  = threadIdx.x;
    const int lane = tid & 63, wid = tid >> 6;

    if (blockIdx.x < TBLOCKS) {
        // ============ target blocks: one wave per (b,t), class NLL ============
        const int tb = blockIdx.x;
        const int b  = tb / TPB;
        const int t  = (tb % TPB) * 4 + wid;

        if (tid < 64)
            prep_targets(target, b, tid, s_gx, s_gy, s_gw, s_gh, s_box, s_gam, s_meta);
        __syncthreads();

        float nll = 0.0f;   // lane-0 of each wave holds this wave's contribution
        if (t < NTT) {
            const int m = s_meta[t];            // wave-uniform
            if (m != 0) {
                // "last valid t wins": skip if any later t has the same cell key
                const int mv_lane = (lane < NTT) ? s_meta[lane] : 0;
                const unsigned long long dup = __ballot(lane > t && mv_lane == m);
                if (dup == 0ULL) {
                    const int best = (m >> 12) & 3;
                    const int hw   = m & 0xFFF;
                    const float* cb = out + ((size_t)(b * NANCH + best) * (5 + NCLS) + 5) * HW + hw;

                    const float l0 = cb[lane * HW];
                    const float l1 = (lane < NCLS - 64) ? cb[(lane + 64) * HW] : -INFINITY;

                    float mx = fmaxf(l0, l1);
                    #pragma unroll
                    for (int off = 32; off > 0; off >>= 1)
                        mx = fmaxf(mx, __shfl_xor(mx, off, 64));

                    float e = __expf(l0 - mx) + ((lane < NCLS - 64) ? __expf(l1 - mx) : 0.0f);
                    #pragma unroll
                    for (int off = 32; off > 0; off >>= 1)
                        e += __shfl_xor(e, off, 64);

                    if (lane == 0) {
                        const int tc = (int)target[b * (NTT * 5) + t * 5];
                        const float lt = cb[tc * HW];
                        nll = -(lt - mx - __logf(e));
                    }
                }
            }
        }
        if (lane == 0) s_part[wid] = nll;
        __syncthreads();
        if (tid == 0)
            partials[blockIdx.x] = s_part[0] + s_part[1] + s_part[2] + s_part[3];
        return;
    }

    // ============ cell blocks ============
    const int cblk = blockIdx.x - TBLOCKS;
    const int b    = cblk / 48;

    const int cell = cblk * 256 + tid;
    const int rem  = cell % (NANCH * HW);
    const int a    = rem / HW;
    const int hw   = rem % HW;
    const int h    = hw >> 6;
    const int w    = hw & 63;

    // issue the 5 strided cell loads before the prep barrier (latency overlap)
    const float* base = out + ((size_t)b * (NANCH * (5 + NCLS)) + (size_t)a * (5 + NCLS)) * HW + hw;
    const float r0 = base[0];
    const float r1 = base[HW];
    const float r2 = base[2 * HW];
    const float r3 = base[3 * HW];
    const float r4 = base[4 * HW];

    if (tid < 64)
        prep_targets(target, b, tid, s_gx, s_gy, s_gw, s_gh, s_box, s_gam, s_meta);
    __syncthreads();

    const float sx = __builtin_amdgcn_rcpf(1.0f + __expf(-r0));
    const float sy = __builtin_amdgcn_rcpf(1.0f + __expf(-r1));

    // reference's anchor-broadcast quirk: effective anchor = (3b+a)//16
    const int aidx = (3 * b + a) >> 4;
    const float aw = aidx == 0 ? AW0 : (aidx == 1 ? AW1 : AW2);
    const float ah = aidx == 0 ? AH0 : (aidx == 1 ? AH1 : AH2);

    const float px = sx + (float)w;
    const float py = sy + (float)h;
    const float pw = __expf(r2) * aw;
    const float ph = __expf(r3) * ah;
    const float parea = pw * ph;

    const float hx0 = px - pw * 0.5f, hx1 = px + pw * 0.5f;
    const float hy0 = py - ph * 0.5f, hy1 = py + ph * 0.5f;

    const int key = (1 << 15) | (a << 12) | (h << 6) | w;

    float curmax = 0.0f;
    int   tlast  = -1;
    #pragma unroll 5
    for (int t = 0; t < NTT; ++t) {
        const float4 bx  = s_box[t];
        const float2 gam = s_gam[t];
        const int    m   = __float_as_int(gam.y);
        // intersection extents: min(hi) - max(lo)  (== w1+w2-(Mx-mx) algebraically)
        const float cw = fminf(hx1, bx.y) - fmaxf(hx0, bx.x);
        const float ch = fminf(hy1, bx.w) - fmaxf(hy0, bx.z);
        const float carea = (cw <= 0.0f || ch <= 0.0f) ? 0.0f : cw * ch;
        const float uarea = parea + gam.x - carea;
        const float iou   = carea * __builtin_amdgcn_rcpf(uarea);
        curmax = fmaxf(curmax, (m != 0) ? iou : 0.0f);
        if (m == key) tlast = t;   // key has valid bit set; last valid t wins
    }

    const float conf = __builtin_amdgcn_rcpf(1.0f + __expf(-r4));
    float lsum;
    if (tlast >= 0) {
        const int best = (s_meta[tlast] >> 12) & 3;
        const float baw = best == 0 ? AW0 : (best == 1 ? AW1 : AW2);
        const float bah = best == 0 ? AH0 : (best == 1 ? AH1 : AH2);
        const float tx = s_gx[tlast] - (float)w;
        const float ty = s_gy[tlast] - (float)h;
        const float tw = __logf(s_gw[tlast] * __builtin_amdgcn_rcpf(baw));
        const float th = __logf(s_gh[tlast] * __builtin_amdgcn_rcpf(bah));

        const float dx = sx - tx, dy = sy - ty, dw = r2 - tw, dh = r3 - th;
        const float dc = conf - 1.0f;
        lsum = dc * dc + 0.5f * (dx * dx + dy * dy + dw * dw + dh * dh);
    } else {
        lsum = (curmax > 0.5f) ? 0.0f : conf * conf;
    }

    // reduce: wave shuffle -> LDS -> one partial store per block (no atomics)
    float v = lsum;
    #pragma unroll
    for (int off = 32; off > 0; off >>= 1) v += __shfl_down(v, off, 64);
    if (lane == 0) s_part[wid] = v;
    __syncthreads();
    if (tid == 0)
        partials[blockIdx.x] = s_part[0] + s_part[1] + s_part[2] + s_part[3];
}

__global__ __launch_bounds__(256) void yolo_reduce_kernel(
    const float* __restrict__ partials, float* __restrict__ loss)
{
    __shared__ float s_part[4];
    const int tid = threadIdx.x;
    float v = 0.0f;
    for (int i = tid; i < NPART; i += 256) v += partials[i];
    #pragma unroll
    for (int off = 32; off > 0; off >>= 1) v += __shfl_down(v, off, 64);
    const int lane = tid & 63, wid = tid >> 6;
    if (lane == 0) s_part[wid] = v;
    __syncthreads();
    if (tid == 0) loss[0] = s_part[0] + s_part[1] + s_part[2] + s_part[3];
}

extern "C" void kernel_launch(void* const* d_in, const int* in_sizes, int n_in,
                              void* d_out, int out_size, void* d_ws, size_t ws_size,
                              hipStream_t stream) {
    const float* out_t  = (const float*)d_in[0];   // (16, 255, 64, 64) f32
    const float* target = (const float*)d_in[1];   // (16, 250) f32
    float* loss     = (float*)d_out;
    float* partials = (float*)d_ws;

    yolo_loss_kernel<<<NPART, 256, 0, stream>>>(out_t, target, partials);
    yolo_reduce_kernel<<<1, 256, 0, stream>>>(partials, loss);
}